// Round 9
// baseline (668.992 us; speedup 1.0000x reference)
//
#include <hip/hip_runtime.h>
#include <hip/hip_bf16.h>
#include <stdint.h>

typedef __bf16 bf16;
typedef __attribute__((ext_vector_type(8))) __bf16 bf16x8;
typedef __attribute__((ext_vector_type(4))) float f32x4;

constexpr int S   = 2048;
constexpr int DH  = 64;
constexpr int BQ  = 16;          // q-rows per block
constexpr int NW  = 4;           // waves per block (256 threads)
constexpr int KPW = S / NW;      // 512 keys per wave
constexpr int NC  = KPW / 32;    // 16 chunks of 32 keys

// Fragment conventions (verified rounds 1-5):
//   mfma(X, Y, acc): X lane(c,g) = X[i=c][k=g*8+j]; Y lane(c,g) = Y[j2=c][k=g*8+j]
//   D lane(c,g) reg r = D[i=g*4+r][j2=c]
// Swapped QK^T mfma(Kfrag, Qfrag) with K-row permutation perm(i)=8*(i>>2)+(i&3):
//   acc0 loads K[k0+perm(c)],   acc1 loads K[k0+perm(c)+4]
//   -> lane(c,g): acc0 reg r = P[key=k0+8g+r][q=c], acc1 reg r = P[key=k0+8g+4+r][q=c]
//   -> lane owns 8 CONTIGUOUS keys k0+8g..k0+8g+7 of q-row c (32B W store, 1-base V
//      reads). Store path VERIFIED clean in r5: WRITE_SIZE = 540.7 MB ideal.
//
// Occupancy model (rounds 1-7): __launch_bounds__ 2nd arg pins waves/EU AND sets
// VGPR budget = 512/arg. 512-thread blocks made every useful arg spill (r4/r6/r7).
// This round: 256-thread block, arg=4 -> budget 128 regs, 16 waves/CU (50%).
// P fully register-resident: pa[16] = 64 VGPR; LDS only 16.6 KB (opart+reduce).

__global__ __launch_bounds__(256, 4)
void attn_fused(const float* __restrict__ Q, const float* __restrict__ K,
                const float* __restrict__ V, const float* __restrict__ Msk,
                float* __restrict__ Out, float* __restrict__ W)
{
    __shared__ float rs[NW][BQ];          // per-wave row-sum partials
    __shared__ float inv[BQ];             // 1/rowsum
    __shared__ float opart[NW][BQ][DH];   // per-wave O partials (16 KB)

    const int tid  = threadIdx.x;
    const int lane = tid & 63;
    const int wave = tid >> 6;            // 0..3
    const int c    = lane & 15;
    const int g    = lane >> 4;           // 0..3

    // XCD-aware swizzle: each XCD gets 512 consecutive swz -> 4 contiguous bh
    const int swz = (blockIdx.x & 7) * 512 + (blockIdx.x >> 3);
    const int bh = swz >> 7;              // 0..31
    const int q0 = (swz & 127) * BQ;

    const float* Qb = Q + (size_t)bh * S * DH;
    const float* Kb = K + (size_t)bh * S * DH;
    const float* Vb = V + (size_t)bh * S * DH;

    // ---- Q fragment (Y-operand): lane(c,g) = Q[q0+c][g*8+j], dh halves lo/hi
    bf16x8 qlo, qhi;
    {
        const float* qr = Qb + (size_t)(q0 + c) * DH + g * 8;
        f32x4 a0 = *(const f32x4*)(qr);
        f32x4 a1 = *(const f32x4*)(qr + 4);
        f32x4 b0 = *(const f32x4*)(qr + 32);
        f32x4 b1 = *(const f32x4*)(qr + 36);
        #pragma unroll
        for (int j = 0; j < 4; ++j) {
            qlo[j]     = (bf16)a0[j];  qlo[j + 4] = (bf16)a1[j];
            qhi[j]     = (bf16)b0[j];  qhi[j + 4] = (bf16)b1[j];
        }
    }

    const int kbase = wave * KPW;                     // wave owns 512 keys
    const int cperm = 8 * (c >> 2) + (c & 3);         // K-row permutation
    const float* mrow = Msk + (size_t)(q0 + c) * S;   // this lane's q-row of the mask

    // =========== Loop 1: QK^T -> exp -> pa regs + row sums (K read once) ===========
    bf16x8 pa[NC];                                    // 64 VGPRs: P register-resident
    float s = 0.f;
    #pragma unroll
    for (int kc = 0; kc < NC; ++kc) {
        const int k0 = kbase + kc * 32;
        const float* kr0 = Kb + (size_t)(k0 + cperm) * DH + g * 8;   // keys k0+perm(c)
        const float* kr1 = kr0 + (size_t)4 * DH;                     // keys k0+perm(c)+4
        f32x4 a0 = *(const f32x4*)(kr0);
        f32x4 a1 = *(const f32x4*)(kr0 + 4);
        f32x4 b0 = *(const f32x4*)(kr0 + 32);
        f32x4 b1 = *(const f32x4*)(kr0 + 36);
        f32x4 a2 = *(const f32x4*)(kr1);
        f32x4 a3 = *(const f32x4*)(kr1 + 4);
        f32x4 b2 = *(const f32x4*)(kr1 + 32);
        f32x4 b3 = *(const f32x4*)(kr1 + 36);
        f32x4 m0 = *(const f32x4*)(mrow + k0 + 8 * g);       // keys k0+8g..+3
        f32x4 m1 = *(const f32x4*)(mrow + k0 + 8 * g + 4);   // keys k0+8g+4..+7

        bf16x8 kl0, kh0, kl1, kh1;
        #pragma unroll
        for (int j = 0; j < 4; ++j) {
            kl0[j] = (bf16)a0[j];  kl0[j + 4] = (bf16)a1[j];
            kh0[j] = (bf16)b0[j];  kh0[j + 4] = (bf16)b1[j];
            kl1[j] = (bf16)a2[j];  kl1[j + 4] = (bf16)a3[j];
            kh1[j] = (bf16)b2[j];  kh1[j + 4] = (bf16)b3[j];
        }
        f32x4 acc0 = {0.f, 0.f, 0.f, 0.f};
        f32x4 acc1 = {0.f, 0.f, 0.f, 0.f};
        acc0 = __builtin_amdgcn_mfma_f32_16x16x32_bf16(kl0, qlo, acc0, 0, 0, 0);
        acc0 = __builtin_amdgcn_mfma_f32_16x16x32_bf16(kh0, qhi, acc0, 0, 0, 0);
        acc1 = __builtin_amdgcn_mfma_f32_16x16x32_bf16(kl1, qlo, acc1, 0, 0, 0);
        acc1 = __builtin_amdgcn_mfma_f32_16x16x32_bf16(kh1, qhi, acc1, 0, 0, 0);

        #pragma unroll
        for (int r = 0; r < 4; ++r) {
            const float p0 = __expf(acc0[r] * 0.125f + m0[r] * (-1e9f));
            const float p1 = __expf(acc1[r] * 0.125f + m1[r] * (-1e9f));
            s += p0 + p1;
            pa[kc][r]     = (bf16)p0;   // key k0+8g+r
            pa[kc][r + 4] = (bf16)p1;   // key k0+8g+4+r
        }
    }

    // reduce over g-groups (same q=c), then across waves
    s += __shfl_xor(s, 16);
    s += __shfl_xor(s, 32);
    if (lane < 16) rs[wave][lane] = s;
    __syncthreads();
    if (tid < BQ) {
        float t = 0.f;
        #pragma unroll
        for (int w = 0; w < NW; ++w) t += rs[w][tid];
        inv[tid] = 1.f / t;
    }
    __syncthreads();
    const float myinv = inv[c];

    // =========== Loop 2: W write (normalized f32, 32B/lane contiguous) + PV ===========
    f32x4 oacc[4] = {{0,0,0,0},{0,0,0,0},{0,0,0,0},{0,0,0,0}};
    float* Wrow = W + (size_t)bh * S * S + (size_t)(q0 + c) * S;

    #pragma unroll
    for (int kc = 0; kc < NC; ++kc) {
        const int k0 = kbase + kc * 32;

        // --- V loads first (independent; overlap with stores): rows k0+8g+j, cols c+16dt
        const float* vp = Vb + (size_t)(k0 + 8 * g) * DH + c;
        float vv[4][8];
        #pragma unroll
        for (int j = 0; j < 8; ++j) {
            #pragma unroll
            for (int dt = 0; dt < 4; ++dt)
                vv[dt][j] = vp[j * DH + dt * 16];
        }

        // --- W write straight from pa regs: keys k0+8g..k0+8g+7 (32B contiguous)
        f32x4 w0, w1;
        #pragma unroll
        for (int r = 0; r < 4; ++r) {
            w0[r] = (float)pa[kc][r]     * myinv;
            w1[r] = (float)pa[kc][r + 4] * myinv;
        }
        *(f32x4*)(Wrow + k0 + 8 * g)     = w0;
        *(f32x4*)(Wrow + k0 + 8 * g + 4) = w1;

        // --- PV: vb slot (g,j) = V[key=k0+8g+j][d=c+16dt] matches pa slot keys
        #pragma unroll
        for (int dt = 0; dt < 4; ++dt) {
            bf16x8 vb;
            #pragma unroll
            for (int j = 0; j < 8; ++j) vb[j] = (bf16)vv[dt][j];
            oacc[dt] = __builtin_amdgcn_mfma_f32_16x16x32_bf16(pa[kc], vb, oacc[dt], 0, 0, 0);
        }
    }

    // --- cross-wave O reduction: lane(c,g) reg r of oacc[dt] = O[q=4g+r][d=16dt+c]
    #pragma unroll
    for (int dt = 0; dt < 4; ++dt)
        #pragma unroll
        for (int r = 0; r < 4; ++r)
            opart[wave][4 * g + r][16 * dt + c] = oacc[dt][r];
    __syncthreads();

    {
        const int q = tid >> 4;            // 0..15
        const int d = (tid & 15) * 4;      // 0..60
        f32x4 o = {0.f, 0.f, 0.f, 0.f};
        #pragma unroll
        for (int w = 0; w < NW; ++w) o += *(const f32x4*)&opart[w][q][d];
        const float is = inv[q];
        o.x *= is; o.y *= is; o.z *= is; o.w *= is;
        float* Ob = Out + ((size_t)bh * S + q0 + q) * DH + d;
        *(f32x4*)Ob = o;
    }
}

extern "C" void kernel_launch(void* const* d_in, const int* in_sizes, int n_in,
                              void* d_out, int out_size, void* d_ws, size_t ws_size,
                              hipStream_t stream) {
    const float* Q   = (const float*)d_in[0];
    const float* K   = (const float*)d_in[1];
    const float* V   = (const float*)d_in[2];
    const float* Msk = (const float*)d_in[3];

    float* Out = (float*)d_out;                       // [2,16,2048,64]
    float* W   = Out + (size_t)2 * 16 * 2048 * 64;    // [2,16,2048,2048]

    dim3 grid(32 * (S / BQ));
    dim3 block(256);
    hipLaunchKernelGGL(attn_fused, grid, block, 0, stream, Q, K, V, Msk, Out, W);
}

// Round 10
// 440.249 us; speedup vs baseline: 1.5196x; 1.5196x over previous
//
#include <hip/hip_runtime.h>
#include <hip/hip_bf16.h>
#include <stdint.h>

typedef __bf16 bf16;
typedef __attribute__((ext_vector_type(8))) __bf16 bf16x8;
typedef __attribute__((ext_vector_type(4))) float f32x4;

constexpr int S   = 2048;
constexpr int DH  = 64;
constexpr int BQ  = 16;          // q-rows per block
constexpr int NW  = 4;           // waves per block (256 threads)
constexpr int KPW = S / NW;      // 512 keys per wave
constexpr int NC  = KPW / 32;    // 16 chunks of 32 keys

// Fragment conventions (verified rounds 1-5):
//   mfma(X, Y, acc): X lane(c,g) = X[i=c][k=g*8+j]; Y lane(c,g) = Y[j2=c][k=g*8+j]
//   D lane(c,g) reg r = D[i=g*4+r][j2=c]
// Swapped QK^T mfma(Kfrag, Qfrag) with K-row permutation perm(i)=8*(i>>2)+(i&3):
//   acc0 loads K[k0+perm(c)],   acc1 loads K[k0+perm(c)+4]
//   -> lane(c,g): acc0 reg r = P[key=k0+8g+r][q=c], acc1 reg r = P[key=k0+8g+4+r][q=c]
//   -> lane owns 8 CONTIGUOUS keys k0+8g..k0+8g+7 of q-row c (32B W store; the
//      wave's 2 stores cover full 128B lines via L2 merge -> WRITE ideal, r5-verified).
//
// Toolchain law (fit to rounds 1-9): __launch_bounds__ 2nd arg caps BOTH
// waves/EU at arg AND VGPRs at ~256/arg. arg>=3 strangles this kernel (<85
// regs -> spill); arg=2 pins occupancy at 25%. Fix: SINGLE-ARG bounds (256):
// VGPR budget 256, no waves pin; natural ~110-130 regs -> hardware gives
// floor(512/VGPR) = 3-4 waves/SIMD = 37-50% occupancy.

__global__ __launch_bounds__(256)
void attn_fused(const float* __restrict__ Q, const float* __restrict__ K,
                const float* __restrict__ V, const float* __restrict__ Msk,
                float* __restrict__ Out, float* __restrict__ W)
{
    __shared__ float rs[NW][BQ];          // per-wave row-sum partials
    __shared__ float inv[BQ];             // 1/rowsum
    __shared__ float opart[NW][BQ][DH];   // per-wave O partials (16 KB)

    const int tid  = threadIdx.x;
    const int lane = tid & 63;
    const int wave = tid >> 6;            // 0..3
    const int c    = lane & 15;
    const int g    = lane >> 4;           // 0..3

    // XCD-aware swizzle: each XCD gets 512 consecutive swz -> 4 contiguous bh
    const int swz = (blockIdx.x & 7) * 512 + (blockIdx.x >> 3);
    const int bh = swz >> 7;              // 0..31
    const int q0 = (swz & 127) * BQ;

    const float* Qb = Q + (size_t)bh * S * DH;
    const float* Kb = K + (size_t)bh * S * DH;
    const float* Vb = V + (size_t)bh * S * DH;

    // ---- Q fragment (Y-operand): lane(c,g) = Q[q0+c][g*8+j], dh halves lo/hi
    bf16x8 qlo, qhi;
    {
        const float* qr = Qb + (size_t)(q0 + c) * DH + g * 8;
        f32x4 a0 = *(const f32x4*)(qr);
        f32x4 a1 = *(const f32x4*)(qr + 4);
        f32x4 b0 = *(const f32x4*)(qr + 32);
        f32x4 b1 = *(const f32x4*)(qr + 36);
        #pragma unroll
        for (int j = 0; j < 4; ++j) {
            qlo[j]     = (bf16)a0[j];  qlo[j + 4] = (bf16)a1[j];
            qhi[j]     = (bf16)b0[j];  qhi[j + 4] = (bf16)b1[j];
        }
    }

    const int kbase = wave * KPW;                     // wave owns 512 keys
    const int cperm = 8 * (c >> 2) + (c & 3);         // K-row permutation
    const float* mrow = Msk + (size_t)(q0 + c) * S;   // this lane's q-row of the mask

    // =========== Loop 1: QK^T -> exp -> pa regs + row sums (K read once) ===========
    bf16x8 pa[NC];                                    // 64 VGPRs: P register-resident
    float s = 0.f;
    #pragma unroll
    for (int kc = 0; kc < NC; ++kc) {
        const int k0 = kbase + kc * 32;
        const float* kr0 = Kb + (size_t)(k0 + cperm) * DH + g * 8;   // keys k0+perm(c)
        const float* kr1 = kr0 + (size_t)4 * DH;                     // keys k0+perm(c)+4
        f32x4 a0 = *(const f32x4*)(kr0);
        f32x4 a1 = *(const f32x4*)(kr0 + 4);
        f32x4 b0 = *(const f32x4*)(kr0 + 32);
        f32x4 b1 = *(const f32x4*)(kr0 + 36);
        f32x4 a2 = *(const f32x4*)(kr1);
        f32x4 a3 = *(const f32x4*)(kr1 + 4);
        f32x4 b2 = *(const f32x4*)(kr1 + 32);
        f32x4 b3 = *(const f32x4*)(kr1 + 36);
        f32x4 m0 = *(const f32x4*)(mrow + k0 + 8 * g);       // keys k0+8g..+3
        f32x4 m1 = *(const f32x4*)(mrow + k0 + 8 * g + 4);   // keys k0+8g+4..+7

        bf16x8 kl0, kh0, kl1, kh1;
        #pragma unroll
        for (int j = 0; j < 4; ++j) {
            kl0[j] = (bf16)a0[j];  kl0[j + 4] = (bf16)a1[j];
            kh0[j] = (bf16)b0[j];  kh0[j + 4] = (bf16)b1[j];
            kl1[j] = (bf16)a2[j];  kl1[j + 4] = (bf16)a3[j];
            kh1[j] = (bf16)b2[j];  kh1[j + 4] = (bf16)b3[j];
        }
        f32x4 acc0 = {0.f, 0.f, 0.f, 0.f};
        f32x4 acc1 = {0.f, 0.f, 0.f, 0.f};
        acc0 = __builtin_amdgcn_mfma_f32_16x16x32_bf16(kl0, qlo, acc0, 0, 0, 0);
        acc0 = __builtin_amdgcn_mfma_f32_16x16x32_bf16(kh0, qhi, acc0, 0, 0, 0);
        acc1 = __builtin_amdgcn_mfma_f32_16x16x32_bf16(kl1, qlo, acc1, 0, 0, 0);
        acc1 = __builtin_amdgcn_mfma_f32_16x16x32_bf16(kh1, qhi, acc1, 0, 0, 0);

        #pragma unroll
        for (int r = 0; r < 4; ++r) {
            const float p0 = __expf(acc0[r] * 0.125f + m0[r] * (-1e9f));
            const float p1 = __expf(acc1[r] * 0.125f + m1[r] * (-1e9f));
            s += p0 + p1;
            pa[kc][r]     = (bf16)p0;   // key k0+8g+r
            pa[kc][r + 4] = (bf16)p1;   // key k0+8g+4+r
        }
    }

    // reduce over g-groups (same q=c), then across waves
    s += __shfl_xor(s, 16);
    s += __shfl_xor(s, 32);
    if (lane < 16) rs[wave][lane] = s;
    __syncthreads();
    if (tid < BQ) {
        float t = 0.f;
        #pragma unroll
        for (int w = 0; w < NW; ++w) t += rs[w][tid];
        inv[tid] = 1.f / t;
    }
    __syncthreads();
    const float myinv = inv[c];

    // =========== Loop 2: W write (normalized f32, 32B/lane contiguous) + PV ===========
    f32x4 oacc[4] = {{0,0,0,0},{0,0,0,0},{0,0,0,0},{0,0,0,0}};
    float* Wrow = W + (size_t)bh * S * S + (size_t)(q0 + c) * S;

    #pragma unroll
    for (int kc = 0; kc < NC; ++kc) {
        const int k0 = kbase + kc * 32;

        // --- V loads first (independent; overlap with stores): rows k0+8g+j, cols c+16dt
        const float* vp = Vb + (size_t)(k0 + 8 * g) * DH + c;
        float vv[4][8];
        #pragma unroll
        for (int j = 0; j < 8; ++j) {
            #pragma unroll
            for (int dt = 0; dt < 4; ++dt)
                vv[dt][j] = vp[j * DH + dt * 16];
        }

        // --- W write straight from pa regs: keys k0+8g..k0+8g+7 (32B contiguous)
        f32x4 w0, w1;
        #pragma unroll
        for (int r = 0; r < 4; ++r) {
            w0[r] = (float)pa[kc][r]     * myinv;
            w1[r] = (float)pa[kc][r + 4] * myinv;
        }
        *(f32x4*)(Wrow + k0 + 8 * g)     = w0;
        *(f32x4*)(Wrow + k0 + 8 * g + 4) = w1;

        // --- PV: vb slot (g,j) = V[key=k0+8g+j][d=c+16dt] matches pa slot keys
        #pragma unroll
        for (int dt = 0; dt < 4; ++dt) {
            bf16x8 vb;
            #pragma unroll
            for (int j = 0; j < 8; ++j) vb[j] = (bf16)vv[dt][j];
            oacc[dt] = __builtin_amdgcn_mfma_f32_16x16x32_bf16(pa[kc], vb, oacc[dt], 0, 0, 0);
        }
    }

    // --- cross-wave O reduction: lane(c,g) reg r of oacc[dt] = O[q=4g+r][d=16dt+c]
    #pragma unroll
    for (int dt = 0; dt < 4; ++dt)
        #pragma unroll
        for (int r = 0; r < 4; ++r)
            opart[wave][4 * g + r][16 * dt + c] = oacc[dt][r];
    __syncthreads();

    {
        const int q = tid >> 4;            // 0..15
        const int d = (tid & 15) * 4;      // 0..60
        f32x4 o = {0.f, 0.f, 0.f, 0.f};
        #pragma unroll
        for (int w = 0; w < NW; ++w) o += *(const f32x4*)&opart[w][q][d];
        const float is = inv[q];
        o.x *= is; o.y *= is; o.z *= is; o.w *= is;
        float* Ob = Out + ((size_t)bh * S + q0 + q) * DH + d;
        *(f32x4*)Ob = o;
    }
}

extern "C" void kernel_launch(void* const* d_in, const int* in_sizes, int n_in,
                              void* d_out, int out_size, void* d_ws, size_t ws_size,
                              hipStream_t stream) {
    const float* Q   = (const float*)d_in[0];
    const float* K   = (const float*)d_in[1];
    const float* V   = (const float*)d_in[2];
    const float* Msk = (const float*)d_in[3];

    float* Out = (float*)d_out;                       // [2,16,2048,64]
    float* W   = Out + (size_t)2 * 16 * 2048 * 64;    // [2,16,2048,2048]

    dim3 grid(32 * (S / BQ));
    dim3 block(256);
    hipLaunchKernelGGL(attn_fused, grid, block, 0, stream, Q, K, V, Msk, Out, W);
}

// Round 11
// 365.974 us; speedup vs baseline: 1.8280x; 1.2030x over previous
//
#include <hip/hip_runtime.h>
#include <hip/hip_bf16.h>
#include <stdint.h>

typedef __bf16 bf16;
typedef __attribute__((ext_vector_type(8))) __bf16 bf16x8;
typedef __attribute__((ext_vector_type(4))) float f32x4;

constexpr int S   = 2048;
constexpr int DH  = 64;
constexpr int BQ  = 16;          // q-rows per block
constexpr int NW  = 4;           // waves per block (256 threads)
constexpr int KPW = S / NW;      // 512 keys per wave
constexpr int NC  = KPW / 32;    // 16 chunks of 32 keys
constexpr int BH  = 32;          // b*H
constexpr size_t ELEMS = (size_t)BH * S * DH;          // 4,194,304
constexpr size_t WS_NEED = ELEMS * 2 * 3;              // Qb,Kb,Vt bf16 = 25.2 MB

// Fragment conventions (verified rounds 1-10):
//   mfma(X, Y, acc): X lane(c,g) = X[i=c][k=g*8+j]; Y lane(c,g) = Y[j2=c][k=g*8+j]
//   D lane(c,g) reg r = D[i=g*4+r][j2=c]
// Swapped QK^T mfma(Kfrag, Qfrag) with K-row permutation perm(i)=8*(i>>2)+(i&3):
//   lane owns 8 CONTIGUOUS keys k0+8g..k0+8g+7 of q-row c. W store path verified
//   ideal (540.7 MB) with plain f32x4 stores.
// This round: QKV pre-cast to bf16 (V transposed to [dh][s]) in d_ws, so the hot
// loops do pure 16B bf16x8 loads with ZERO cvt — fewer bytes, fewer VALU ops,
// shorter dep chains, lower reg pressure -> deeper load pipelining.

// ---------- pre-kernel 1: cast K and Q to bf16 (same layout) ----------
__global__ __launch_bounds__(256)
void cast_kq(const float* __restrict__ K, const float* __restrict__ Q,
             bf16* __restrict__ Kb, bf16* __restrict__ Qb)
{
    const size_t t = (size_t)blockIdx.x * 256 + threadIdx.x;   // 0..ELEMS/8-1
    {
        const float* src = K + t * 8;
        f32x4 a = *(const f32x4*)(src);
        f32x4 b = *(const f32x4*)(src + 4);
        bf16x8 o;
        #pragma unroll
        for (int j = 0; j < 4; ++j) { o[j] = (bf16)a[j]; o[j + 4] = (bf16)b[j]; }
        *(bf16x8*)(Kb + t * 8) = o;
    }
    {
        const float* src = Q + t * 8;
        f32x4 a = *(const f32x4*)(src);
        f32x4 b = *(const f32x4*)(src + 4);
        bf16x8 o;
        #pragma unroll
        for (int j = 0; j < 4; ++j) { o[j] = (bf16)a[j]; o[j + 4] = (bf16)b[j]; }
        *(bf16x8*)(Qb + t * 8) = o;
    }
}

// ---------- pre-kernel 2: cast + transpose V -> Vt[bh][dh][s] bf16 ----------
__global__ __launch_bounds__(256)
void transpose_v(const float* __restrict__ V, bf16* __restrict__ Vt)
{
    __shared__ bf16 t[64][72];            // 64x64 tile, padded row
    const int bh = blockIdx.x >> 5;
    const int sb = (blockIdx.x & 31) * 64;
    const int tid = threadIdx.x;

    {   // load 64 s-rows x 64 d, coalesced f32x4 x4 per thread
        const int r  = tid >> 2;          // s-row 0..63
        const int c0 = (tid & 3) * 16;    // d base
        const float* src = V + ((size_t)bh * S + sb + r) * DH + c0;
        f32x4 v0 = *(const f32x4*)(src);
        f32x4 v1 = *(const f32x4*)(src + 4);
        f32x4 v2 = *(const f32x4*)(src + 8);
        f32x4 v3 = *(const f32x4*)(src + 12);
        #pragma unroll
        for (int j = 0; j < 4; ++j) {
            t[r][c0 + j]      = (bf16)v0[j];
            t[r][c0 + 4 + j]  = (bf16)v1[j];
            t[r][c0 + 8 + j]  = (bf16)v2[j];
            t[r][c0 + 12 + j] = (bf16)v3[j];
        }
    }
    __syncthreads();
    {   // store transposed: thread owns d-row, 16 s values (2x 16B)
        const int d  = tid >> 2;          // 0..63
        const int s0 = (tid & 3) * 16;
        bf16x8 o0, o1;
        #pragma unroll
        for (int j = 0; j < 8; ++j) { o0[j] = t[s0 + j][d]; o1[j] = t[s0 + 8 + j][d]; }
        bf16* dst = Vt + ((size_t)bh * DH + d) * S + sb + s0;
        *(bf16x8*)(dst)     = o0;
        *(bf16x8*)(dst + 8) = o1;
    }
}

// ---------- main kernel (bf16 inputs from ws) ----------
__global__ __launch_bounds__(256)
void attn_fused_b16(const bf16* __restrict__ Qb, const bf16* __restrict__ Kb,
                    const bf16* __restrict__ Vt, const float* __restrict__ Msk,
                    float* __restrict__ Out, float* __restrict__ W)
{
    __shared__ float rs[NW][BQ];
    __shared__ float inv[BQ];
    __shared__ float opart[NW][BQ][DH];   // 16 KB

    const int tid  = threadIdx.x;
    const int lane = tid & 63;
    const int wave = tid >> 6;            // 0..3
    const int c    = lane & 15;
    const int g    = lane >> 4;           // 0..3

    const int swz = (blockIdx.x & 7) * 512 + (blockIdx.x >> 3);
    const int bh = swz >> 7;
    const int q0 = (swz & 127) * BQ;

    const bf16* Qbb = Qb + (size_t)bh * S * DH;
    const bf16* Kbb = Kb + (size_t)bh * S * DH;
    const bf16* Vtb = Vt + (size_t)bh * DH * S;

    // ---- Q fragment: two 16B loads
    const bf16* qr = Qbb + (size_t)(q0 + c) * DH + g * 8;
    bf16x8 qlo = *(const bf16x8*)(qr);
    bf16x8 qhi = *(const bf16x8*)(qr + 32);

    const int kbase = wave * KPW;
    const int cperm = 8 * (c >> 2) + (c & 3);
    const float* mrow = Msk + (size_t)(q0 + c) * S;

    // =========== Loop 1: QK^T -> exp -> pa regs + row sums ===========
    bf16x8 pa[NC];
    float s = 0.f;
    #pragma unroll
    for (int kc = 0; kc < NC; ++kc) {
        const int k0 = kbase + kc * 32;
        const bf16* kr = Kbb + (size_t)(k0 + cperm) * DH + g * 8;
        bf16x8 kl0 = *(const bf16x8*)(kr);
        bf16x8 kh0 = *(const bf16x8*)(kr + 32);
        bf16x8 kl1 = *(const bf16x8*)(kr + 4 * DH);
        bf16x8 kh1 = *(const bf16x8*)(kr + 4 * DH + 32);
        f32x4 m0 = *(const f32x4*)(mrow + k0 + 8 * g);
        f32x4 m1 = *(const f32x4*)(mrow + k0 + 8 * g + 4);

        f32x4 acc0 = {0.f, 0.f, 0.f, 0.f};
        f32x4 acc1 = {0.f, 0.f, 0.f, 0.f};
        acc0 = __builtin_amdgcn_mfma_f32_16x16x32_bf16(kl0, qlo, acc0, 0, 0, 0);
        acc0 = __builtin_amdgcn_mfma_f32_16x16x32_bf16(kh0, qhi, acc0, 0, 0, 0);
        acc1 = __builtin_amdgcn_mfma_f32_16x16x32_bf16(kl1, qlo, acc1, 0, 0, 0);
        acc1 = __builtin_amdgcn_mfma_f32_16x16x32_bf16(kh1, qhi, acc1, 0, 0, 0);

        #pragma unroll
        for (int r = 0; r < 4; ++r) {
            const float p0 = __expf(acc0[r] * 0.125f + m0[r] * (-1e9f));
            const float p1 = __expf(acc1[r] * 0.125f + m1[r] * (-1e9f));
            s += p0 + p1;
            pa[kc][r]     = (bf16)p0;   // key k0+8g+r
            pa[kc][r + 4] = (bf16)p1;   // key k0+8g+4+r
        }
    }

    s += __shfl_xor(s, 16);
    s += __shfl_xor(s, 32);
    if (lane < 16) rs[wave][lane] = s;
    __syncthreads();
    if (tid < BQ) {
        float t = 0.f;
        #pragma unroll
        for (int w = 0; w < NW; ++w) t += rs[w][tid];
        inv[tid] = 1.f / t;
    }
    __syncthreads();
    const float myinv = inv[c];

    // =========== Loop 2: W write + PV (V^T: pure 16B loads, zero cvt) ===========
    f32x4 oacc[4] = {{0,0,0,0},{0,0,0,0},{0,0,0,0},{0,0,0,0}};
    float* Wrow = W + (size_t)bh * S * S + (size_t)(q0 + c) * S;

    #pragma unroll
    for (int kc = 0; kc < NC; ++kc) {
        const int k0 = kbase + kc * 32;

        // V fragments: vb[dt] slot j = V[key k0+8g+j][d=16dt+c] = Vt[16dt+c][k0+8g+j]
        const bf16* vp = Vtb + (size_t)c * S + k0 + 8 * g;
        bf16x8 vb0 = *(const bf16x8*)(vp);
        bf16x8 vb1 = *(const bf16x8*)(vp + (size_t)16 * S);
        bf16x8 vb2 = *(const bf16x8*)(vp + (size_t)32 * S);
        bf16x8 vb3 = *(const bf16x8*)(vp + (size_t)48 * S);

        // W write straight from pa regs: keys k0+8g..+7 (32B/lane contiguous)
        f32x4 w0, w1;
        #pragma unroll
        for (int r = 0; r < 4; ++r) {
            w0[r] = (float)pa[kc][r]     * myinv;
            w1[r] = (float)pa[kc][r + 4] * myinv;
        }
        *(f32x4*)(Wrow + k0 + 8 * g)     = w0;
        *(f32x4*)(Wrow + k0 + 8 * g + 4) = w1;

        oacc[0] = __builtin_amdgcn_mfma_f32_16x16x32_bf16(pa[kc], vb0, oacc[0], 0, 0, 0);
        oacc[1] = __builtin_amdgcn_mfma_f32_16x16x32_bf16(pa[kc], vb1, oacc[1], 0, 0, 0);
        oacc[2] = __builtin_amdgcn_mfma_f32_16x16x32_bf16(pa[kc], vb2, oacc[2], 0, 0, 0);
        oacc[3] = __builtin_amdgcn_mfma_f32_16x16x32_bf16(pa[kc], vb3, oacc[3], 0, 0, 0);
    }

    // cross-wave O reduction: lane(c,g) reg r of oacc[dt] = O[q=4g+r][d=16dt+c]
    #pragma unroll
    for (int dt = 0; dt < 4; ++dt)
        #pragma unroll
        for (int r = 0; r < 4; ++r)
            opart[wave][4 * g + r][16 * dt + c] = oacc[dt][r];
    __syncthreads();

    {
        const int q = tid >> 4;
        const int d = (tid & 15) * 4;
        f32x4 o = {0.f, 0.f, 0.f, 0.f};
        #pragma unroll
        for (int w = 0; w < NW; ++w) o += *(const f32x4*)&opart[w][q][d];
        const float is = inv[q];
        o.x *= is; o.y *= is; o.z *= is; o.w *= is;
        float* Ob = Out + ((size_t)bh * S + q0 + q) * DH + d;
        *(f32x4*)Ob = o;
    }
}

// ---------- fallback (r10 kernel, f32 direct) used if ws too small ----------
__global__ __launch_bounds__(256)
void attn_fused_f32(const float* __restrict__ Q, const float* __restrict__ K,
                    const float* __restrict__ V, const float* __restrict__ Msk,
                    float* __restrict__ Out, float* __restrict__ W)
{
    __shared__ float rs[NW][BQ];
    __shared__ float inv[BQ];
    __shared__ float opart[NW][BQ][DH];

    const int tid  = threadIdx.x;
    const int lane = tid & 63;
    const int wave = tid >> 6;
    const int c    = lane & 15;
    const int g    = lane >> 4;

    const int swz = (blockIdx.x & 7) * 512 + (blockIdx.x >> 3);
    const int bh = swz >> 7;
    const int q0 = (swz & 127) * BQ;

    const float* Qb = Q + (size_t)bh * S * DH;
    const float* Kb = K + (size_t)bh * S * DH;
    const float* Vb = V + (size_t)bh * S * DH;

    bf16x8 qlo, qhi;
    {
        const float* qr = Qb + (size_t)(q0 + c) * DH + g * 8;
        f32x4 a0 = *(const f32x4*)(qr);
        f32x4 a1 = *(const f32x4*)(qr + 4);
        f32x4 b0 = *(const f32x4*)(qr + 32);
        f32x4 b1 = *(const f32x4*)(qr + 36);
        #pragma unroll
        for (int j = 0; j < 4; ++j) {
            qlo[j]     = (bf16)a0[j];  qlo[j + 4] = (bf16)a1[j];
            qhi[j]     = (bf16)b0[j];  qhi[j + 4] = (bf16)b1[j];
        }
    }

    const int kbase = wave * KPW;
    const int cperm = 8 * (c >> 2) + (c & 3);
    const float* mrow = Msk + (size_t)(q0 + c) * S;

    bf16x8 pa[NC];
    float s = 0.f;
    #pragma unroll
    for (int kc = 0; kc < NC; ++kc) {
        const int k0 = kbase + kc * 32;
        const float* kr0 = Kb + (size_t)(k0 + cperm) * DH + g * 8;
        const float* kr1 = kr0 + (size_t)4 * DH;
        f32x4 a0 = *(const f32x4*)(kr0);
        f32x4 a1 = *(const f32x4*)(kr0 + 4);
        f32x4 b0 = *(const f32x4*)(kr0 + 32);
        f32x4 b1 = *(const f32x4*)(kr0 + 36);
        f32x4 a2 = *(const f32x4*)(kr1);
        f32x4 a3 = *(const f32x4*)(kr1 + 4);
        f32x4 b2 = *(const f32x4*)(kr1 + 32);
        f32x4 b3 = *(const f32x4*)(kr1 + 36);
        f32x4 m0 = *(const f32x4*)(mrow + k0 + 8 * g);
        f32x4 m1 = *(const f32x4*)(mrow + k0 + 8 * g + 4);

        bf16x8 kl0, kh0, kl1, kh1;
        #pragma unroll
        for (int j = 0; j < 4; ++j) {
            kl0[j] = (bf16)a0[j];  kl0[j + 4] = (bf16)a1[j];
            kh0[j] = (bf16)b0[j];  kh0[j + 4] = (bf16)b1[j];
            kl1[j] = (bf16)a2[j];  kl1[j + 4] = (bf16)a3[j];
            kh1[j] = (bf16)b2[j];  kh1[j + 4] = (bf16)b3[j];
        }
        f32x4 acc0 = {0.f, 0.f, 0.f, 0.f};
        f32x4 acc1 = {0.f, 0.f, 0.f, 0.f};
        acc0 = __builtin_amdgcn_mfma_f32_16x16x32_bf16(kl0, qlo, acc0, 0, 0, 0);
        acc0 = __builtin_amdgcn_mfma_f32_16x16x32_bf16(kh0, qhi, acc0, 0, 0, 0);
        acc1 = __builtin_amdgcn_mfma_f32_16x16x32_bf16(kl1, qlo, acc1, 0, 0, 0);
        acc1 = __builtin_amdgcn_mfma_f32_16x16x32_bf16(kh1, qhi, acc1, 0, 0, 0);

        #pragma unroll
        for (int r = 0; r < 4; ++r) {
            const float p0 = __expf(acc0[r] * 0.125f + m0[r] * (-1e9f));
            const float p1 = __expf(acc1[r] * 0.125f + m1[r] * (-1e9f));
            s += p0 + p1;
            pa[kc][r]     = (bf16)p0;
            pa[kc][r + 4] = (bf16)p1;
        }
    }

    s += __shfl_xor(s, 16);
    s += __shfl_xor(s, 32);
    if (lane < 16) rs[wave][lane] = s;
    __syncthreads();
    if (tid < BQ) {
        float t = 0.f;
        #pragma unroll
        for (int w = 0; w < NW; ++w) t += rs[w][tid];
        inv[tid] = 1.f / t;
    }
    __syncthreads();
    const float myinv = inv[c];

    f32x4 oacc[4] = {{0,0,0,0},{0,0,0,0},{0,0,0,0},{0,0,0,0}};
    float* Wrow = W + (size_t)bh * S * S + (size_t)(q0 + c) * S;

    #pragma unroll
    for (int kc = 0; kc < NC; ++kc) {
        const int k0 = kbase + kc * 32;
        const float* vp = Vb + (size_t)(k0 + 8 * g) * DH + c;
        float vv[4][8];
        #pragma unroll
        for (int j = 0; j < 8; ++j) {
            #pragma unroll
            for (int dt = 0; dt < 4; ++dt)
                vv[dt][j] = vp[j * DH + dt * 16];
        }
        f32x4 w0, w1;
        #pragma unroll
        for (int r = 0; r < 4; ++r) {
            w0[r] = (float)pa[kc][r]     * myinv;
            w1[r] = (float)pa[kc][r + 4] * myinv;
        }
        *(f32x4*)(Wrow + k0 + 8 * g)     = w0;
        *(f32x4*)(Wrow + k0 + 8 * g + 4) = w1;

        #pragma unroll
        for (int dt = 0; dt < 4; ++dt) {
            bf16x8 vb;
            #pragma unroll
            for (int j = 0; j < 8; ++j) vb[j] = (bf16)vv[dt][j];
            oacc[dt] = __builtin_amdgcn_mfma_f32_16x16x32_bf16(pa[kc], vb, oacc[dt], 0, 0, 0);
        }
    }

    #pragma unroll
    for (int dt = 0; dt < 4; ++dt)
        #pragma unroll
        for (int r = 0; r < 4; ++r)
            opart[wave][4 * g + r][16 * dt + c] = oacc[dt][r];
    __syncthreads();

    {
        const int q = tid >> 4;
        const int d = (tid & 15) * 4;
        f32x4 o = {0.f, 0.f, 0.f, 0.f};
        #pragma unroll
        for (int w = 0; w < NW; ++w) o += *(const f32x4*)&opart[w][q][d];
        const float is = inv[q];
        o.x *= is; o.y *= is; o.z *= is; o.w *= is;
        float* Ob = Out + ((size_t)bh * S + q0 + q) * DH + d;
        *(f32x4*)Ob = o;
    }
}

extern "C" void kernel_launch(void* const* d_in, const int* in_sizes, int n_in,
                              void* d_out, int out_size, void* d_ws, size_t ws_size,
                              hipStream_t stream) {
    const float* Q   = (const float*)d_in[0];
    const float* K   = (const float*)d_in[1];
    const float* V   = (const float*)d_in[2];
    const float* Msk = (const float*)d_in[3];

    float* Out = (float*)d_out;                       // [2,16,2048,64]
    float* W   = Out + (size_t)2 * 16 * 2048 * 64;    // [2,16,2048,2048]

    if (ws_size >= WS_NEED) {
        bf16* Kb = (bf16*)d_ws;
        bf16* Vt = Kb + ELEMS;
        bf16* Qb = Vt + ELEMS;
        hipLaunchKernelGGL(cast_kq, dim3(ELEMS / 8 / 256), dim3(256), 0, stream,
                           K, Q, Kb, Qb);
        hipLaunchKernelGGL(transpose_v, dim3(BH * (S / 64)), dim3(256), 0, stream,
                           V, Vt);
        hipLaunchKernelGGL(attn_fused_b16, dim3(BH * (S / BQ)), dim3(256), 0, stream,
                           Qb, Kb, Vt, Msk, Out, W);
    } else {
        hipLaunchKernelGGL(attn_fused_f32, dim3(BH * (S / BQ)), dim3(256), 0, stream,
                           Q, K, V, Msk, Out, W);
    }
}